// Round 1
// 191.592 us; speedup vs baseline: 1.0160x; 1.0160x over previous
//
#include <hip/hip_runtime.h>
#include <hip/hip_bf16.h>
#include <math.h>

#define T_LEN 20000
#define HID 150

typedef __attribute__((ext_vector_type(8))) __bf16 bf16x8;
typedef __attribute__((ext_vector_type(4))) float f32x4;

__device__ __forceinline__ short f2bf(float f) {
    unsigned u = __float_as_uint(f);
    u = (u + 0x7fff + ((u >> 16) & 1)) >> 16;
    return (short)u;
}

__device__ __forceinline__ unsigned pk2(float a, float b) {
    __hip_bfloat162 h = __float22bfloat162_rn(make_float2(a, b));
    return *(unsigned*)&h;
}

__device__ __forceinline__ bf16x8 cvt8(float4 a, float4 b) {
    union { unsigned u[4]; bf16x8 v; } r;
    r.u[0] = pk2(a.x, a.y);
    r.u[1] = pk2(a.z, a.w);
    r.u[2] = pk2(b.x, b.y);
    r.u[3] = pk2(b.z, b.w);
    return r.v;
}

__device__ __forceinline__ float2 ubf2(unsigned u) {
    return make_float2(__uint_as_float(u << 16),
                       __uint_as_float(u & 0xffff0000u));
}

// ---------------------------------------------------------------------------
// Fragment-order weight regions (shorts), lane = consuming lane (ml|kg<<4):
//   fragA  [0,199680)        30 tiles x 13 ks x 64 x 8   U(0-9) V(10-19) aW1(20-29)
//   fragP  [199680,250880)   10 tiles x 10 ks x 64 x 8   sc_W1 rows 800..1099
//   fragAt2[250880,276480)   10 tiles x  5 ks x 64 x 8   attn_W2
//   fragW2 [276480,302080)   10 tiles x  5 ks x 64 x 8   sc_W2
// frag[((tile*KS+ks)*64+lane)*8+e] = W[k=ks*32+(lane>>4)*8+e][col=tile*16+(lane&15)]
// ---------------------------------------------------------------------------
__global__ __launch_bounds__(256) void wprep(
    const float* __restrict__ sc_W1, const float* __restrict__ attn_W1,
    const float* __restrict__ attn_W2, const float* __restrict__ sc_W2,
    short* __restrict__ frag)
{
    int t = blockIdx.x * 256 + threadIdx.x;
    if (t >= 302080) return;
    float v = 0.f;
    if (t < 199680) {
        int e = t & 7, g = t >> 3;
        int lane = g & 63, h = g >> 6;
        int ks = h % 13, nt = h / 13;
        int k = ks * 32 + (lane >> 4) * 8 + e;
        int cs = (nt % 10) * 16 + (lane & 15);
        if (k < 400 && cs < HID) {
            if (nt < 10)      v = sc_W1[(long)k * HID + cs];
            else if (nt < 20) v = sc_W1[(long)(400 + k) * HID + cs];
            else              v = attn_W1[(long)k * HID + cs];
        }
    } else if (t < 250880) {
        int r = t - 199680;
        int e = r & 7, g = r >> 3;
        int lane = g & 63, h = g >> 6;
        int ks = h % 10, nt = h / 10;
        int k = ks * 32 + (lane >> 4) * 8 + e;
        int cs = nt * 16 + (lane & 15);
        if (k < 300 && cs < HID) v = sc_W1[(long)(800 + k) * HID + cs];
    } else if (t < 276480) {
        int r = t - 250880;
        int e = r & 7, g = r >> 3;
        int lane = g & 63, h = g >> 6;
        int ks = h % 5, nt = h / 5;
        int k = ks * 32 + (lane >> 4) * 8 + e;
        int cs = nt * 16 + (lane & 15);
        if (k < HID && cs < HID) v = attn_W2[(long)k * HID + cs];
    } else {
        int r = t - 276480;
        int e = r & 7, g = r >> 3;
        int lane = g & 63, h = g >> 6;
        int ks = h % 5, nt = h / 5;
        int k = ks * 32 + (lane >> 4) * 8 + e;
        int cs = nt * 16 + (lane & 15);
        if (k < HID && cs < HID) v = sc_W2[(long)k * HID + cs];
    }
    frag[t] = f2bf(v);
}

// ---------------------------------------------------------------------------
// Batched tile GEMM inner loop: per ks, 1 conflict-free ds_read_b128 for the
// A-fragment (pre-staged in LDS in fragment layout) + NT independent 16B
// global loads of weight fragments held in registers, THEN NT MFMAs.
// Keeps ~NT vmem loads in flight per wave (vs ~1-2 in the 44-VGPR version).
// ---------------------------------------------------------------------------
template<int NT, int KS>
__device__ __forceinline__ void mm_tiles(
    const short* __restrict__ fb,   // frag region base + lane*8
    const short* As,                // LDS A fragments: [(ks*64+lane)*8]
    int w, int lane, f32x4* acc)
{
    #pragma unroll
    for (int ks = 0; ks < KS; ++ks) {
        bf16x8 af = *(const bf16x8*)&As[(ks * 64 + lane) * 8];
        bf16x8 bfr[NT];
        #pragma unroll
        for (int t = 0; t < NT; ++t)
            bfr[t] = *(const bf16x8*)&fb[((4 * t + w) * KS + ks) << 9];
        #pragma unroll
        for (int t = 0; t < NT; ++t)
            acc[t] = __builtin_amdgcn_mfma_f32_16x16x32_bf16(bfr[t], af, acc[t], 0, 0, 0);
    }
}

// ---------------------------------------------------------------------------
// fusedAP v2: 16 rows/block, grid 1250.
//   - A (states, then embeds) staged ONCE per block into LDS, bf16, in exact
//     fragment layout -> ds_read_b128 per ks, no per-wave redundant cvt.
//   - frag loads batched per ks (mm_tiles) for vmem ILP.
//   Phase A: states @ {U,V,aW1}   Phase B: embeds @ P   Phase C: attn 2/3.
// ---------------------------------------------------------------------------
__global__ __launch_bounds__(256, 4) void fusedAP(
    const float* __restrict__ states, const float* __restrict__ embeds,
    const short* __restrict__ frag,
    const float* __restrict__ scb1, const float* __restrict__ ab1,
    const float* __restrict__ ab2, const float* __restrict__ aW3,
    const float* __restrict__ ab3,
    short* __restrict__ Ubf, short* __restrict__ Vbf, short* __restrict__ Pbf,
    float* __restrict__ logits)
{
    __shared__ short As[13 * 64 * 8];     // 13312 B: A fragments (reused for embeds)
    __shared__ short h1s[16 * 168];
    __shared__ float red[16][4];
    __shared__ float sb1[160], ab1s[160];
    const int tid = threadIdx.x;
    const int w = tid >> 6, lane = tid & 63;
    const int ml = lane & 15, kg = lane >> 4;
    const int m0 = blockIdx.x * 16;          // 1250 * 16 = 20000 exact

    for (int t = tid; t < 160; t += 256) {
        sb1[t]  = (t < HID) ? scb1[t] : 0.f;
        ab1s[t] = (t < HID) ? ab1[t]  : 0.f;
    }
    // ---- stage states (16 rows x K=400) into As, fragment layout ----
    for (int g = tid; g < 13 * 64; g += 256) {
        int ks = g >> 6, l2 = g & 63;
        int k = ks * 32 + ((l2 >> 4) << 3);
        const float* Ar = states + (long)(m0 + (l2 & 15)) * 400;
        float4 a0 = make_float4(0.f, 0.f, 0.f, 0.f), a1 = a0;
        if (k + 4 <= 400) a0 = *(const float4*)&Ar[k];
        if (k + 8 <= 400) a1 = *(const float4*)&Ar[k + 4];
        *(bf16x8*)&As[g * 8] = cvt8(a0, a1);
    }
    __syncthreads();

    // ---------------- Phase A: states @ {U,V,aW1} ----------------
    f32x4 acc[8];
    #pragma unroll
    for (int t = 0; t < 8; ++t) acc[t] = (f32x4){0.f, 0.f, 0.f, 0.f};
    const short* fb = frag + lane * 8;
    if (w < 2) mm_tiles<8, 13>(fb, As, w, lane, acc);
    else       mm_tiles<7, 13>(fb, As, w, lane, acc);

    const int nT = (w < 2) ? 8 : 7;
    #pragma unroll
    for (int t = 0; t < 8; ++t) {
        if (t < nT) {
            int nt = 4 * t + w;
            if (nt < 10) {                    // U (+sc_b1)
                int col0 = nt * 16 + kg * 4;
                float v[4];
                #pragma unroll
                for (int r = 0; r < 4; ++r) {
                    int c = col0 + r;
                    v[r] = (c < HID) ? acc[t][r] + sb1[c] : 0.f;
                }
                *(uint2*)&Ubf[(long)(m0 + ml) * 160 + col0] =
                    make_uint2(pk2(v[0], v[1]), pk2(v[2], v[3]));
            } else if (nt < 20) {             // V
                int col0 = (nt - 10) * 16 + kg * 4;
                float v[4];
                #pragma unroll
                for (int r = 0; r < 4; ++r) {
                    int c = col0 + r;
                    v[r] = (c < HID) ? acc[t][r] : 0.f;
                }
                *(uint2*)&Vbf[(long)(m0 + ml) * 160 + col0] =
                    make_uint2(pk2(v[0], v[1]), pk2(v[2], v[3]));
            } else {                          // X1 -> relu -> bf16 LDS
                int col0 = (nt - 20) * 16 + kg * 4;
                float v[4];
                #pragma unroll
                for (int r = 0; r < 4; ++r) {
                    int c = col0 + r;
                    v[r] = (c < HID) ? fmaxf(acc[t][r] + ab1s[c], 0.f) : 0.f;
                }
                *(uint2*)&h1s[ml * 168 + col0] =
                    make_uint2(pk2(v[0], v[1]), pk2(v[2], v[3]));
            }
        }
    }
    __syncthreads();   // As reads done + h1s complete

    // ---- restage embeds (16 rows x K=300) into As ----
    for (int g = tid; g < 10 * 64; g += 256) {
        int ks = g >> 6, l2 = g & 63;
        int k = ks * 32 + ((l2 >> 4) << 3);
        const float* Er = embeds + (long)(m0 + (l2 & 15)) * 300;
        float4 a0 = make_float4(0.f, 0.f, 0.f, 0.f), a1 = a0;
        if (k + 4 <= 300) a0 = *(const float4*)&Er[k];
        if (k + 8 <= 300) a1 = *(const float4*)&Er[k + 4];
        *(bf16x8*)&As[g * 8] = cvt8(a0, a1);
    }
    __syncthreads();

    // ---------------- Phase B: embeds @ P-slice ----------------
    {
        f32x4 accP[3];
        #pragma unroll
        for (int t = 0; t < 3; ++t) accP[t] = (f32x4){0.f, 0.f, 0.f, 0.f};
        const short* fP = frag + 199680 + lane * 8;
        if (w < 2) mm_tiles<3, 10>(fP, As, w, lane, accP);
        else       mm_tiles<2, 10>(fP, As, w, lane, accP);

        const int nTp = (w < 2) ? 3 : 2;
        #pragma unroll
        for (int t = 0; t < 3; ++t) {
            if (t < nTp) {
                int nt = 4 * t + w;
                int col0 = nt * 16 + kg * 4;
                float v[4];
                #pragma unroll
                for (int r = 0; r < 4; ++r) {
                    int c = col0 + r;
                    v[r] = (c < HID) ? accP[t][r] : 0.f;
                }
                *(uint2*)&Pbf[(long)(m0 + ml) * 160 + col0] =
                    make_uint2(pk2(v[0], v[1]), pk2(v[2], v[3]));
            }
        }
    }

    // ---------------- Phase C: attn layers 2+3 ----------------
    const short* fAt2 = frag + 250880 + lane * 8;
    bf16x8 af2[5];
    #pragma unroll
    for (int ks = 0; ks < 5; ++ks)
        af2[ks] = *(const bf16x8*)&h1s[ml * 168 + ks * 32 + kg * 8];

    const int nT2 = (w < 2) ? 3 : 2;
    float score[4] = {0.f, 0.f, 0.f, 0.f};
    #pragma unroll
    for (int t = 0; t < 3; ++t) {
        if (t < nT2) {
            int nt = 4 * t + w;
            bf16x8 wb[5];
            #pragma unroll
            for (int ks = 0; ks < 5; ++ks)
                wb[ks] = *(const bf16x8*)&fAt2[(nt * 5 + ks) << 9];
            f32x4 a2 = {0.f, 0.f, 0.f, 0.f};
            #pragma unroll
            for (int ks = 0; ks < 5; ++ks)
                a2 = __builtin_amdgcn_mfma_f32_16x16x32_bf16(af2[ks], wb[ks], a2, 0, 0, 0);
            int col = nt * 16 + ml;
            float b2v = (col < HID) ? ab2[col] : 0.f;
            float w3v = (col < HID) ? aW3[col] : 0.f;
            #pragma unroll
            for (int r = 0; r < 4; ++r)
                score[r] += fmaxf(a2[r] + b2v, 0.f) * w3v;
        }
    }
    #pragma unroll
    for (int r = 0; r < 4; ++r) {
        score[r] += __shfl_xor(score[r], 1);
        score[r] += __shfl_xor(score[r], 2);
        score[r] += __shfl_xor(score[r], 4);
        score[r] += __shfl_xor(score[r], 8);
    }
    if (ml == 0) {
        #pragma unroll
        for (int r = 0; r < 4; ++r) red[kg * 4 + r][w] = score[r];
    }
    __syncthreads();
    if (tid < 16)
        logits[m0 + tid] = red[tid][0] + red[tid][1] + red[tid][2] + red[tid][3] + ab3[0];
}

// ---------------------------------------------------------------------------
// span_all: grid (625, 2). Block (x,y): 32 spans of chunk x, widths n in
// {1..5} (y=0) or {6..10} (y=1, 5-row L2-hit prefix). SOFTWARE-PIPELINED:
// double-buffered h1s/red, phase1(n+1) overlaps phase2(n), ONE sync per n.
// v2: af ds_reads hoisted above phase1 overlap; fW2 fragment group double-
// buffered across the j-loop (wc/wn) so next tile's 5 L2 loads fly under the
// current MFMA chain + epilogue.
// ---------------------------------------------------------------------------
__global__ __launch_bounds__(256) void span_all(
    const short* __restrict__ Ubf, const short* __restrict__ Vbf,
    const short* __restrict__ Pbf, const float* __restrict__ logits,
    const short* __restrict__ fW2, const float* __restrict__ b2,
    const float* __restrict__ W3, const float* __restrict__ b3,
    float* __restrict__ out)
{
    __shared__ short h1s[2][32 * 168];
    __shared__ float red[2][32][2];
    __shared__ float Ls[48], ebuf[48];
    __shared__ float b2s[160], W3s[160];

    const int tid = threadIdx.x;
    const int s0 = blockIdx.x * 32;
    const int nlo = blockIdx.y ? 6 : 1;
    const int nhi = blockIdx.y ? 10 : 5;

    if (tid < 48) {
        int r = s0 + tid; if (r > T_LEN - 1) r = T_LEN - 1;
        Ls[tid] = (tid < 41) ? logits[r] : -1e30f;
    }
    for (int t = tid; t < 160; t += 256) {
        b2s[t] = (t < HID) ? b2[t] : 0.f;
        W3s[t] = (t < HID) ? W3[t] : 0.f;
    }
    __syncthreads();
    if (tid < 48) {
        float M = -1e30f;
        for (int t = 0; t < 41; ++t) M = fmaxf(M, Ls[t]);
        ebuf[tid] = (tid < 41) ? expf(Ls[tid] - M) : 0.f;
    }
    __syncthreads();

    const int i = tid >> 3;       // span 0..31
    const int q = tid & 7;        // dim block [20q, 20q+20)
    const int d0 = 20 * q;
    const int s = s0 + i;
    int su = s; if (su > T_LEN - 1) su = T_LEN - 1;

    float Ur[20];
    {
        const uint2* U2 = (const uint2*)&Ubf[(long)su * 160 + d0];
        #pragma unroll
        for (int c = 0; c < 5; ++c) {
            uint2 uv = U2[c];
            float2 a = ubf2(uv.x), b_ = ubf2(uv.y);
            Ur[4 * c + 0] = a.x;  Ur[4 * c + 1] = a.y;
            Ur[4 * c + 2] = b_.x; Ur[4 * c + 3] = b_.y;
        }
    }
    float accp[20];
    #pragma unroll
    for (int d = 0; d < 20; ++d) accp[d] = 0.f;
    float den = 0.f;

    // prefix j = 0..nlo-2 (only y=1: 5 rows, L2-hit)
    for (int j = 0; j < nlo - 1; ++j) {
        int rr_ = s + j; if (rr_ > T_LEN - 1) rr_ = T_LEN - 1;
        float e = ebuf[i + j];
        den += e;
        const uint2* P2 = (const uint2*)&Pbf[(long)rr_ * 160 + d0];
        #pragma unroll
        for (int c = 0; c < 5; ++c) {
            uint2 pv = P2[c];
            float2 a = ubf2(pv.x), b_ = ubf2(pv.y);
            accp[4 * c + 0] += e * a.x;  accp[4 * c + 1] += e * a.y;
            accp[4 * c + 2] += e * b_.x; accp[4 * c + 3] += e * b_.y;
        }
    }

    const int w = tid >> 6, lane = tid & 63;
    const int ml = lane & 15, kg = lane >> 4;
    const int mt = w >> 1;            // m-tile (spans mt*16..+15)
    const int nt0 = (w & 1) * 5;      // nt half
    const float bb = b3[0];
    const short* fw = fW2 + ((nt0 * 5) << 9) + lane * 8;

    // phase1 for n: update accp/den, write h1 -> h1s[p]
    auto phase1 = [&](int n, int p) {
        int rr_ = s + n - 1; if (rr_ > T_LEN - 1) rr_ = T_LEN - 1;
        float e = ebuf[i + n - 1];
        den += e;
        {
            const uint2* P2 = (const uint2*)&Pbf[(long)rr_ * 160 + d0];
            #pragma unroll
            for (int c = 0; c < 5; ++c) {
                uint2 pv = P2[c];
                float2 a = ubf2(pv.x), b_ = ubf2(pv.y);
                accp[4 * c + 0] += e * a.x;  accp[4 * c + 1] += e * a.y;
                accp[4 * c + 2] += e * b_.x; accp[4 * c + 3] += e * b_.y;
            }
        }
        float invd = 1.f / den;
        {
            const uint2* V2 = (const uint2*)&Vbf[(long)rr_ * 160 + d0];
            #pragma unroll
            for (int c = 0; c < 5; ++c) {
                uint2 vv = V2[c];
                float2 a = ubf2(vv.x), b_ = ubf2(vv.y);
                float x0 = fmaxf(Ur[4 * c + 0] + a.x  + accp[4 * c + 0] * invd, 0.f);
                float x1 = fmaxf(Ur[4 * c + 1] + a.y  + accp[4 * c + 1] * invd, 0.f);
                float x2 = fmaxf(Ur[4 * c + 2] + b_.x + accp[4 * c + 2] * invd, 0.f);
                float x3 = fmaxf(Ur[4 * c + 3] + b_.y + accp[4 * c + 3] * invd, 0.f);
                *(uint2*)&h1s[p][i * 168 + d0 + 4 * c] =
                    make_uint2(pk2(x0, x1), pk2(x2, x3));
            }
        }
    };

    phase1(nlo, 0);
    __syncthreads();

    for (int n = nlo; n <= nhi; ++n) {
        const int p = (n - nlo) & 1;

        // phase-2 LDS operands for n: issue before the overlapped phase1
        bf16x8 af[5];
        #pragma unroll
        for (int ks = 0; ks < 5; ++ks)
            af[ks] = *(const bf16x8*)&h1s[p][(mt * 16 + ml) * 168 + ks * 32 + kg * 8];

        // phase 1 for n+1 into the other buffer (overlaps loads + MFMAs)
        if (n < nhi) phase1(n + 1, 1 - p);

        // phase 2 on h1s[p]: j-loop with double-buffered fW2 fragments
        bf16x8 wc[5], wn[5];
        #pragma unroll
        for (int ks = 0; ks < 5; ++ks)
            wc[ks] = *(const bf16x8*)&fw[ks << 9];

        float sc[4] = {0.f, 0.f, 0.f, 0.f};
        #pragma unroll
        for (int j = 0; j < 5; ++j) {
            if (j < 4) {
                #pragma unroll
                for (int ks = 0; ks < 5; ++ks)
                    wn[ks] = *(const bf16x8*)&fw[((j + 1) * 5 + ks) << 9];
            }
            f32x4 a2 = {0.f, 0.f, 0.f, 0.f};
            #pragma unroll
            for (int ks = 0; ks < 5; ++ks)
                a2 = __builtin_amdgcn_mfma_f32_16x16x32_bf16(af[ks], wc[ks], a2, 0, 0, 0);
            int col = (nt0 + j) * 16 + ml;
            float b2v = b2s[col], w3v = W3s[col];
            #pragma unroll
            for (int r = 0; r < 4; ++r)
                sc[r] += fmaxf(a2[r] + b2v, 0.f) * w3v;
            #pragma unroll
            for (int ks = 0; ks < 5; ++ks) wc[ks] = wn[ks];
        }
        #pragma unroll
        for (int r = 0; r < 4; ++r) {
            sc[r] += __shfl_xor(sc[r], 1);
            sc[r] += __shfl_xor(sc[r], 2);
            sc[r] += __shfl_xor(sc[r], 4);
            sc[r] += __shfl_xor(sc[r], 8);
        }
        if (ml == 0) {
            #pragma unroll
            for (int r = 0; r < 4; ++r)
                red[p][mt * 16 + kg * 4 + r][w & 1] = sc[r];
        }
        __syncthreads();
        if (tid < 32) {
            int S = T_LEN - n + 1;
            int off = (n - 1) * (T_LEN + 1) - (n - 1) * n / 2;
            int sr = s0 + tid;
            if (sr < S) out[off + sr] = red[p][tid][0] + red[p][tid][1] + bb;
        }
    }
}

// ---------------------------------------------------------------------------
extern "C" void kernel_launch(void* const* d_in, const int* in_sizes, int n_in,
                              void* d_out, int out_size, void* d_ws, size_t ws_size,
                              hipStream_t stream) {
    const float* embeds  = (const float*)d_in[0];
    const float* states  = (const float*)d_in[1];
    const float* attn_W1 = (const float*)d_in[2];
    const float* attn_b1 = (const float*)d_in[3];
    const float* attn_W2 = (const float*)d_in[4];
    const float* attn_b2 = (const float*)d_in[5];
    const float* attn_W3 = (const float*)d_in[6];
    const float* attn_b3 = (const float*)d_in[7];
    const float* sc_W1   = (const float*)d_in[8];
    const float* sc_b1   = (const float*)d_in[9];
    const float* sc_W2   = (const float*)d_in[10];
    const float* sc_b2   = (const float*)d_in[11];
    const float* sc_W3   = (const float*)d_in[12];
    const float* sc_b3   = (const float*)d_in[13];
    float* out = (float*)d_out;

    short* wsS = (short*)d_ws;
    short* Ubf = wsS;                         // [20000][160] bf16
    short* Vbf = wsS + 3200256;
    short* Pbf = wsS + 6400512;
    short* frag = wsS + 9600768;              // 302,080 shorts
    float* logits = (float*)(wsS + 9902848);  // 20,000 floats

    wprep<<<1180, 256, 0, stream>>>(sc_W1, attn_W1, attn_W2, sc_W2, frag);
    fusedAP<<<1250, 256, 0, stream>>>(states, embeds, frag, sc_b1, attn_b1,
                                      attn_b2, attn_W3, attn_b3,
                                      Ubf, Vbf, Pbf, logits);
    span_all<<<dim3(625, 2), 256, 0, stream>>>(Ubf, Vbf, Pbf, logits,
                                               frag + 276480, sc_b2, sc_W3, sc_b3,
                                               out);
}